// Round 5
// baseline (226.857 us; speedup 1.0000x reference)
//
#include <hip/hip_runtime.h>

typedef _Float16 f16;
typedef _Float16 half8 __attribute__((ext_vector_type(8)));
typedef float f32x4 __attribute__((ext_vector_type(4)));
typedef unsigned int u32x4 __attribute__((ext_vector_type(4)));

#define RES 1024
#define NH 16
#define HD 64
#define BATCH 2
#define SEQ 2048
#define M_ROWS (BATCH * SEQ)

// 0.125 (1/sqrt(64)) * log2(e); folded into Qh so flash softmax is a bare v_exp
#define QSCALE 0.18033688011112043f

#if __has_builtin(__builtin_amdgcn_exp2f)
#define EXP2(x) __builtin_amdgcn_exp2f(x)
#else
#define EXP2(x) exp2f(x)
#endif

__device__ __forceinline__ void gload_lds16(const void* g, void* l) {
  __builtin_amdgcn_global_load_lds(
      (const __attribute__((address_space(1))) unsigned int*)g,
      (__attribute__((address_space(3))) unsigned int*)l, 16, 0, 0);
}

// pack two f32 -> one u32 of two f16 (round-toward-zero, single VALU op)
__device__ __forceinline__ unsigned pk16(float a, float b) {
  auto h = __builtin_amdgcn_cvt_pkrtz(a, b);  // __fp16 ext_vector(2)
  return __builtin_bit_cast(unsigned, h);
}

// x' = [a_lo32, b_lo32], y' = [a_hi32, b_hi32]
__device__ __forceinline__ void swap32(unsigned a, unsigned b, unsigned& x, unsigned& y) {
#if __has_builtin(__builtin_amdgcn_permlane32_swap)
  auto t = __builtin_amdgcn_permlane32_swap(a, b, false, false);
  x = (unsigned)t[0];
  y = (unsigned)t[1];
#else
  unsigned ax = __shfl_xor(a, 32), bx = __shfl_xor(b, 32);
  int hi = (threadIdx.x & 63) >> 5;
  x = hi ? bx : a;
  y = hi ? b : ax;
#endif
}

// rows of 16 lanes: x' = [a0,b0,a2,b2], y' = [a1,b1,a3,b3]
__device__ __forceinline__ void swap16(unsigned a, unsigned b, unsigned& x, unsigned& y) {
#if __has_builtin(__builtin_amdgcn_permlane16_swap)
  auto t = __builtin_amdgcn_permlane16_swap(a, b, false, false);
  x = (unsigned)t[0];
  y = (unsigned)t[1];
#else
  unsigned ax = __shfl_xor(a, 16), bx = __shfl_xor(b, 16);
  int q1 = ((threadIdx.x & 63) >> 4) & 1;
  x = q1 ? bx : a;
  y = q1 ? b : ax;
#endif
}

// ---------------- x: fp32 -> fp16 ----------------
__global__ __launch_bounds__(256) void xconv_kernel(const float* __restrict__ x,
                                                    f16* __restrict__ xh) {
  int idx = blockIdx.x * 256 + threadIdx.x;  // 8 floats per thread
  const float4* xv = (const float4*)x;
  float4 a = xv[idx * 2];
  float4 b = xv[idx * 2 + 1];
  half8 h;
  h[0] = (f16)a.x; h[1] = (f16)a.y; h[2] = (f16)a.z; h[3] = (f16)a.w;
  h[4] = (f16)b.x; h[5] = (f16)b.y; h[6] = (f16)b.z; h[7] = (f16)b.w;
  ((half8*)xh)[idx] = h;
}

// ---------------- W: fp32 [K,N] -> fp16 W^T [N,K] ----------------
__global__ __launch_bounds__(1024) void wtrans_kernel(const float* __restrict__ Wq,
                                                      const float* __restrict__ Wk,
                                                      const float* __restrict__ Wv,
                                                      f16* __restrict__ Wt) {
  const float* W = blockIdx.z == 0 ? Wq : (blockIdx.z == 1 ? Wk : Wv);
  f16* Wo = Wt + (size_t)blockIdx.z * RES * RES;
  __shared__ float tile[32][33];
  int n = blockIdx.x * 32 + threadIdx.x;
  int k = blockIdx.y * 32 + threadIdx.y;
  tile[threadIdx.y][threadIdx.x] = W[(size_t)k * RES + n];
  __syncthreads();
  int ko = blockIdx.y * 32 + threadIdx.x;
  int no = blockIdx.x * 32 + threadIdx.y;
  Wo[(size_t)no * RES + ko] = (f16)tile[threadIdx.x][threadIdx.y];
}

// ---------------- projections: C = x @ W  (B^T layout), m97-style ----------------
// writes Qh (pre-scaled by 0.125*log2e -> flash uses bare exp2) / Kh as
// [b,h,s,d], V transposed as Vt [b,h,d,s]
__global__ __launch_bounds__(256) void proj_gemm_kernel(const f16* __restrict__ xh,
                                                        const f16* __restrict__ Wt,
                                                        f16* __restrict__ Qh,
                                                        f16* __restrict__ Kh,
                                                        f16* __restrict__ Vt) {
  int proj = blockIdx.z;
  const f16* Bt = Wt + (size_t)proj * RES * RES;
  int m0 = blockIdx.x * 128;
  int n0 = blockIdx.y * 128;
  __shared__ alignas(16) f16 Als[128 * 32];
  __shared__ alignas(16) f16 Bls[128 * 32];
  int t = threadIdx.x, lane = t & 63, w = t >> 6;
  int l15 = lane & 15, quad = lane >> 4;
  int wm = w >> 1, wn = w & 1;

  f32x4 zero = {0.f, 0.f, 0.f, 0.f};
  f32x4 acc[4][4];
#pragma unroll
  for (int mt = 0; mt < 4; mt++)
#pragma unroll
    for (int nt = 0; nt < 4; nt++) acc[mt][nt] = zero;

  for (int k0 = 0; k0 < RES; k0 += 32) {
#pragma unroll
    for (int i = 0; i < 2; i++) {
      int wl = i * 256 + w * 64;   // wave-uniform linear base
      int linear = wl + lane;      // per-lane
      int row = linear >> 2;
      int kk = (linear & 3) * 8;
      gload_lds16(xh + (size_t)(m0 + row) * RES + k0 + kk, &Als[wl * 8]);
      gload_lds16(Bt + (size_t)(n0 + row) * RES + k0 + kk, &Bls[wl * 8]);
    }
    __syncthreads();
    half8 af[4], bf[4];
#pragma unroll
    for (int mt = 0; mt < 4; mt++)
      af[mt] = *(const half8*)&Als[(wm * 64 + mt * 16 + l15) * 32 + quad * 8];
#pragma unroll
    for (int nt = 0; nt < 4; nt++)
      bf[nt] = *(const half8*)&Bls[(wn * 64 + nt * 16 + l15) * 32 + quad * 8];
#pragma unroll
    for (int mt = 0; mt < 4; mt++)
#pragma unroll
      for (int nt = 0; nt < 4; nt++)
        acc[mt][nt] = __builtin_amdgcn_mfma_f32_16x16x32_f16(af[mt], bf[nt], acc[mt][nt], 0, 0, 0);
    __syncthreads();
  }

#pragma unroll
  for (int mt = 0; mt < 4; mt++) {
#pragma unroll
    for (int nt = 0; nt < 4; nt++) {
#pragma unroll
      for (int r = 0; r < 4; r++) {
        int row = m0 + wm * 64 + mt * 16 + quad * 4 + r;  // 0..4095
        int col = n0 + wn * 64 + nt * 16 + l15;           // 0..1023
        float raw = acc[mt][nt][r];
        int b = row >> 11, s = row & (SEQ - 1);
        int h = col >> 6, d = col & (HD - 1);
        size_t bh = (size_t)b * NH + h;
        if (proj == 0)
          Qh[(bh * SEQ + s) * HD + d] = (f16)(raw * QSCALE);
        else if (proj == 1)
          Kh[(bh * SEQ + s) * HD + d] = (f16)raw;
        else
          Vt[(bh * HD + d) * SEQ + s] = (f16)raw;
      }
    }
  }
}

// ---------------- flash attention (v12) ----------------
// v12 = round-2-verified v9 base + two unbundled changes (v11's split/combine
// reverted after numeric failure):
//  (1) 128 KV rows per barrier pair: two v9-identical 64-row sub-tiles A,B
//      (Kls[2]/Vls[2], 32.8KB). Per super-iter: barrier -> A: kf/QK/sm/pack/
//      vf/PV_A -> B: kf/QK/sm/pack/vf -> barrier -> stage A'+B' -> PV_B.
//      Halves the barrier+vmcnt-drain count (64 -> 32); PV_A gives the LDS
//      unit slack between A-reads and B-reads. Staging/read addressing is
//      byte-for-byte v9 per sub-tile.
//  (2) exp2 prescale: Qh pre-scaled by 0.125*log2e at proj, bare v_exp here
//      (removes ~64 v_mul per old iter from the softmax chain).
// Kept from v9: 2 waves x 32q, XCD swizzle, S^T form, fixed-m softmax,
// XOR-swizzled staging, in-register P repack, stage-after-reads-barrier.
__global__ __launch_bounds__(128, 3) void flash_kernel(const f16* __restrict__ Qh,
                                                       const f16* __restrict__ Kh,
                                                       const f16* __restrict__ Vt,
                                                       float* __restrict__ out) {
  int L = blockIdx.x;
  int xcd = L & 7, slot = L >> 3;
  int bh = ((slot >> 5) << 3) | xcd;  // 32 qt-blocks of bh share one XCD
  int qt = slot & 31;
  int b = bh >> 4, h = bh & 15;
  int tid = threadIdx.x;
  int lane = tid & 63, w = tid >> 6;  // w in {0,1}
  int l15 = lane & 15, quad = lane >> 4;
  int qrow0 = qt * 64 + w * 32;

  __shared__ alignas(16) f16 Kls[2][64 * 64];  // [sub][t][d], XOR chunk swizzle by row&7
  __shared__ alignas(16) f16 Vls[2][64 * 64];  // [sub][d][t], same swizzle

  const f16* kbase = Kh + (size_t)bh * SEQ * HD;
  const f16* vbase = Vt + (size_t)bh * HD * SEQ;

  // staging map: 128 threads, 4 rounds x (K,V); round rd covers rows rd*16 + (tid>>3)
  int srow = tid >> 3;  // 0..15
  int schunk = tid & 7;

  // Q fragments (B-operand for S^T = K Q^T), 2 q-tiles; scale pre-folded in Qh
  const f16* qptr = Qh + ((size_t)bh * SEQ + qrow0 + l15) * HD + quad * 8;
  half8 qf[2][2];
  qf[0][0] = *(const half8*)qptr;
  qf[0][1] = *(const half8*)(qptr + 32);
  qf[1][0] = *(const half8*)(qptr + 16 * HD);
  qf[1][1] = *(const half8*)(qptr + 16 * HD + 32);

  f32x4 zero = {0.f, 0.f, 0.f, 0.f};
  float l_acc[2] = {0.f, 0.f};
  f32x4 o[2][4];
#pragma unroll
  for (int q2 = 0; q2 < 2; q2++)
#pragma unroll
    for (int nt = 0; nt < 4; nt++) o[q2][nt] = zero;

  // swizzled LDS read offsets (halves): row*64 + (chunk ^ (row&7))*8
  int swz0 = (quad ^ (l15 & 7)) * 8;        // log chunks 0..3
  int swz1 = ((quad + 4) ^ (l15 & 7)) * 8;  // log chunks 4..7

  // cooperative staging of one 64-row sub-tile (v9-identical addressing)
  auto stage = [&](int kv0, int sub) {
#pragma unroll
    for (int rd = 0; rd < 4; rd++) {
      int row = rd * 16 + srow;
      int pc = schunk ^ (row & 7);
      gload_lds16(kbase + ((size_t)(kv0 + row) << 6) + pc * 8,
                  &Kls[sub][rd * 1024 + w * 512]);
      gload_lds16(vbase + ((size_t)row * SEQ) + kv0 + pc * 8,
                  &Vls[sub][rd * 1024 + w * 512]);
    }
  };

  // QK^T + softmax + in-register P repack for one sub-tile (v9-identical)
  auto qkt = [&](const f16* Kb, half8 (&pa)[2][2]) {
    half8 kf0[4], kf1[4];
#pragma unroll
    for (int tt = 0; tt < 4; tt++) {
      int row = tt * 16 + l15;
      kf0[tt] = *(const half8*)&Kb[row * 64 + swz0];
      kf1[tt] = *(const half8*)&Kb[row * 64 + swz1];
    }
#pragma unroll
    for (int q2 = 0; q2 < 2; q2++) {
      f32x4 sc[4];
#pragma unroll
      for (int tt = 0; tt < 4; tt++) {
        sc[tt] = __builtin_amdgcn_mfma_f32_16x16x32_f16(kf0[tt], qf[q2][0], zero, 0, 0, 0);
        sc[tt] = __builtin_amdgcn_mfma_f32_16x16x32_f16(kf1[tt], qf[q2][1], sc[tt], 0, 0, 0);
      }
      float ps = 0.f;
#pragma unroll
      for (int tt = 0; tt < 4; tt++)
#pragma unroll
        for (int r = 0; r < 4; r++) { sc[tt][r] = EXP2(sc[tt][r]); ps += sc[tt][r]; }
      ps += __shfl_xor(ps, 16);
      ps += __shfl_xor(ps, 32);
      l_acc[q2] += ps;

      unsigned wp[4][2];
#pragma unroll
      for (int tt = 0; tt < 4; tt++) {
        wp[tt][0] = pk16(sc[tt][0], sc[tt][1]);
        wp[tt][1] = pk16(sc[tt][2], sc[tt][3]);
      }
#pragma unroll
      for (int ks = 0; ks < 2; ks++) {
        u32x4 pw;
#pragma unroll
        for (int i = 0; i < 2; i++) {
          unsigned a, bb, x, y;
          swap32(wp[2 * ks][i], wp[2 * ks + 1][i], a, bb);
          swap16(a, bb, x, y);
          pw[i] = x;
          pw[2 + i] = y;
        }
        pa[q2][ks] = __builtin_bit_cast(half8, pw);
      }
    }
  };

  auto vload = [&](const f16* Vb, half8 (&vf0)[4], half8 (&vf1)[4]) {
#pragma unroll
    for (int nt = 0; nt < 4; nt++) {
      int row = nt * 16 + l15;
      vf0[nt] = *(const half8*)&Vb[row * 64 + swz0];
      vf1[nt] = *(const half8*)&Vb[row * 64 + swz1];
    }
  };

  auto pv = [&](half8 (&pa)[2][2], half8 (&vf0)[4], half8 (&vf1)[4]) {
#pragma unroll
    for (int q2 = 0; q2 < 2; q2++)
#pragma unroll
      for (int ks = 0; ks < 2; ks++)
#pragma unroll
        for (int nt = 0; nt < 4; nt++)
          o[q2][nt] = __builtin_amdgcn_mfma_f32_16x16x32_f16(pa[q2][ks], ks ? vf1[nt] : vf0[nt], o[q2][nt], 0, 0, 0);
  };

  stage(0, 0);
  stage(64, 1);

  constexpr int NT = SEQ / 128;  // 16 super-iterations
  for (int it = 0; it < NT; ++it) {
    int kv0 = it * 128;
    __syncthreads();  // both staged sub-tiles resident (barrier drains vmcnt)

    // ---- sub A: full pipeline incl. PV (register-only after reads) ----
    {
      half8 paA[2][2], vA0[4], vA1[4];
      qkt(&Kls[0][0], paA);
      vload(&Vls[0][0], vA0, vA1);
      pv(paA, vA0, vA1);
    }
    // ---- sub B: up to vf; PV deferred past staging ----
    half8 paB[2][2], vB0[4], vB1[4];
    qkt(&Kls[1][0], paB);
    vload(&Vls[1][0], vB0, vB1);

    __syncthreads();  // all LDS reads of both sub-tiles complete

    if (it + 1 < NT) {
      stage(kv0 + 128, 0);  // issue next pair; latency hides under PV_B
      stage(kv0 + 192, 1);
    }
    pv(paB, vB0, vB1);
  }

#pragma unroll
  for (int q2 = 0; q2 < 2; q2++) {
    float linv[4];
#pragma unroll
    for (int r = 0; r < 4; r++) linv[r] = 1.0f / __shfl(l_acc[q2], quad * 4 + r);
#pragma unroll
    for (int nt = 0; nt < 4; nt++) {
#pragma unroll
      for (int r = 0; r < 4; r++) {
        int s = qrow0 + q2 * 16 + quad * 4 + r;
        out[((size_t)b * SEQ + s) * RES + h * HD + nt * 16 + l15] = o[q2][nt][r] * linv[r];
      }
    }
  }
}

extern "C" void kernel_launch(void* const* d_in, const int* in_sizes, int n_in,
                              void* d_out, int out_size, void* d_ws, size_t ws_size,
                              hipStream_t stream) {
  (void)in_sizes; (void)n_in; (void)out_size; (void)ws_size;
  const float* x  = (const float*)d_in[0];
  const float* Wq = (const float*)d_in[1];
  const float* Wk = (const float*)d_in[2];
  const float* Wv = (const float*)d_in[3];
  float* out = (float*)d_out;

  // workspace layout (fp16): xh 8MB | Wt 6MB | Qh 8MB | Kh 8MB | Vt 8MB = 38MB
  f16* xh = (f16*)d_ws;
  f16* Wt = xh + (size_t)M_ROWS * RES;
  f16* Qh = Wt + (size_t)3 * RES * RES;
  f16* Kh = Qh + (size_t)BATCH * NH * SEQ * HD;
  f16* Vt = Kh + (size_t)BATCH * NH * SEQ * HD;

  xconv_kernel<<<M_ROWS * RES / (256 * 8), 256, 0, stream>>>(x, xh);
  wtrans_kernel<<<dim3(32, 32, 3), dim3(32, 32), 0, stream>>>(Wq, Wk, Wv, Wt);
  proj_gemm_kernel<<<dim3(M_ROWS / 128, RES / 128, 3), 256, 0, stream>>>(xh, Wt, Qh, Kh, Vt);
  flash_kernel<<<1024, 128, 0, stream>>>(Qh, Kh, Vt, out);
}

// Round 9
// 166.947 us; speedup vs baseline: 1.3589x; 1.3589x over previous
//
#include <hip/hip_runtime.h>

typedef _Float16 f16;
typedef _Float16 half8 __attribute__((ext_vector_type(8)));
typedef float f32x4 __attribute__((ext_vector_type(4)));
typedef unsigned int u32x4 __attribute__((ext_vector_type(4)));

#define RES 1024
#define NH 16
#define HD 64
#define BATCH 2
#define SEQ 2048
#define M_ROWS (BATCH * SEQ)

__device__ __forceinline__ void gload_lds16(const void* g, void* l) {
  __builtin_amdgcn_global_load_lds(
      (const __attribute__((address_space(1))) unsigned int*)g,
      (__attribute__((address_space(3))) unsigned int*)l, 16, 0, 0);
}

// pack two f32 -> one u32 of two f16 (round-toward-zero, single VALU op)
__device__ __forceinline__ unsigned pk16(float a, float b) {
  auto h = __builtin_amdgcn_cvt_pkrtz(a, b);  // __fp16 ext_vector(2)
  return __builtin_bit_cast(unsigned, h);
}

// x' = [a_lo32, b_lo32], y' = [a_hi32, b_hi32]
__device__ __forceinline__ void swap32(unsigned a, unsigned b, unsigned& x, unsigned& y) {
#if __has_builtin(__builtin_amdgcn_permlane32_swap)
  auto t = __builtin_amdgcn_permlane32_swap(a, b, false, false);
  x = (unsigned)t[0];
  y = (unsigned)t[1];
#else
  unsigned ax = __shfl_xor(a, 32), bx = __shfl_xor(b, 32);
  int hi = (threadIdx.x & 63) >> 5;
  x = hi ? bx : a;
  y = hi ? b : ax;
#endif
}

// rows of 16 lanes: x' = [a0,b0,a2,b2], y' = [a1,b1,a3,b3]
__device__ __forceinline__ void swap16(unsigned a, unsigned b, unsigned& x, unsigned& y) {
#if __has_builtin(__builtin_amdgcn_permlane16_swap)
  auto t = __builtin_amdgcn_permlane16_swap(a, b, false, false);
  x = (unsigned)t[0];
  y = (unsigned)t[1];
#else
  unsigned ax = __shfl_xor(a, 16), bx = __shfl_xor(b, 16);
  int q1 = ((threadIdx.x & 63) >> 4) & 1;
  x = q1 ? bx : a;
  y = q1 ? b : ax;
#endif
}

// ---------------- x: fp32 -> fp16 ----------------
__global__ __launch_bounds__(256) void xconv_kernel(const float* __restrict__ x,
                                                    f16* __restrict__ xh) {
  int idx = blockIdx.x * 256 + threadIdx.x;  // 8 floats per thread
  const float4* xv = (const float4*)x;
  float4 a = xv[idx * 2];
  float4 b = xv[idx * 2 + 1];
  half8 h;
  h[0] = (f16)a.x; h[1] = (f16)a.y; h[2] = (f16)a.z; h[3] = (f16)a.w;
  h[4] = (f16)b.x; h[5] = (f16)b.y; h[6] = (f16)b.z; h[7] = (f16)b.w;
  ((half8*)xh)[idx] = h;
}

// ---------------- W: fp32 [K,N] -> fp16 W^T [N,K] ----------------
__global__ __launch_bounds__(1024) void wtrans_kernel(const float* __restrict__ Wq,
                                                      const float* __restrict__ Wk,
                                                      const float* __restrict__ Wv,
                                                      f16* __restrict__ Wt) {
  const float* W = blockIdx.z == 0 ? Wq : (blockIdx.z == 1 ? Wk : Wv);
  f16* Wo = Wt + (size_t)blockIdx.z * RES * RES;
  __shared__ float tile[32][33];
  int n = blockIdx.x * 32 + threadIdx.x;
  int k = blockIdx.y * 32 + threadIdx.y;
  tile[threadIdx.y][threadIdx.x] = W[(size_t)k * RES + n];
  __syncthreads();
  int ko = blockIdx.y * 32 + threadIdx.x;
  int no = blockIdx.x * 32 + threadIdx.y;
  Wo[(size_t)no * RES + ko] = (f16)tile[threadIdx.x][threadIdx.y];
}

// ---------------- projections: C = x @ W  (B^T layout), m97-style ----------------
// writes Qh/Kh as [b,h,s,d], V transposed as Vt [b,h,d,s]
__global__ __launch_bounds__(256) void proj_gemm_kernel(const f16* __restrict__ xh,
                                                        const f16* __restrict__ Wt,
                                                        f16* __restrict__ Qh,
                                                        f16* __restrict__ Kh,
                                                        f16* __restrict__ Vt) {
  int proj = blockIdx.z;
  const f16* Bt = Wt + (size_t)proj * RES * RES;
  int m0 = blockIdx.x * 128;
  int n0 = blockIdx.y * 128;
  __shared__ alignas(16) f16 Als[128 * 32];
  __shared__ alignas(16) f16 Bls[128 * 32];
  int t = threadIdx.x, lane = t & 63, w = t >> 6;
  int l15 = lane & 15, quad = lane >> 4;
  int wm = w >> 1, wn = w & 1;

  f32x4 zero = {0.f, 0.f, 0.f, 0.f};
  f32x4 acc[4][4];
#pragma unroll
  for (int mt = 0; mt < 4; mt++)
#pragma unroll
    for (int nt = 0; nt < 4; nt++) acc[mt][nt] = zero;

  for (int k0 = 0; k0 < RES; k0 += 32) {
#pragma unroll
    for (int i = 0; i < 2; i++) {
      int wl = i * 256 + w * 64;   // wave-uniform linear base
      int linear = wl + lane;      // per-lane
      int row = linear >> 2;
      int kk = (linear & 3) * 8;
      gload_lds16(xh + (size_t)(m0 + row) * RES + k0 + kk, &Als[wl * 8]);
      gload_lds16(Bt + (size_t)(n0 + row) * RES + k0 + kk, &Bls[wl * 8]);
    }
    __syncthreads();
    half8 af[4], bf[4];
#pragma unroll
    for (int mt = 0; mt < 4; mt++)
      af[mt] = *(const half8*)&Als[(wm * 64 + mt * 16 + l15) * 32 + quad * 8];
#pragma unroll
    for (int nt = 0; nt < 4; nt++)
      bf[nt] = *(const half8*)&Bls[(wn * 64 + nt * 16 + l15) * 32 + quad * 8];
#pragma unroll
    for (int mt = 0; mt < 4; mt++)
#pragma unroll
      for (int nt = 0; nt < 4; nt++)
        acc[mt][nt] = __builtin_amdgcn_mfma_f32_16x16x32_f16(af[mt], bf[nt], acc[mt][nt], 0, 0, 0);
    __syncthreads();
  }

#pragma unroll
  for (int mt = 0; mt < 4; mt++) {
#pragma unroll
    for (int nt = 0; nt < 4; nt++) {
#pragma unroll
      for (int r = 0; r < 4; r++) {
        int row = m0 + wm * 64 + mt * 16 + quad * 4 + r;  // 0..4095
        int col = n0 + wn * 64 + nt * 16 + l15;           // 0..1023
        f16 v = (f16)acc[mt][nt][r];
        int b = row >> 11, s = row & (SEQ - 1);
        int h = col >> 6, d = col & (HD - 1);
        size_t bh = (size_t)b * NH + h;
        if (proj == 0)
          Qh[(bh * SEQ + s) * HD + d] = v;
        else if (proj == 1)
          Kh[(bh * SEQ + s) * HD + d] = v;
        else
          Vt[(bh * HD + d) * SEQ + s] = v;
      }
    }
  }
}

// ---------------- flash attention (v16 = round-2-verified v9, verbatim) ----------------
// v16 is an EXACT revert to the round-2 passing kernel (170.87us total,
// flash 58-65us). Post-mortem clustering across 8 rounds: non-QSCALE class
// 3/3 PASS (r0/r2/r3); QSCALE/EXP2 class 1/5 pass (v11-v15; v15 had no KV
// split and still failed with the same ~0.1 signature, exonerating the
// split and implicating the QSCALE/EXP2 substitution via elimination --
// mechanism not modeled, so it is OUT per rigor discipline).
// v9 structure: P never touches LDS (cvt_pkrtz + permlane32/16_swap repack
// to the PV A-fragment layout); next-tile staging issued after the
// reads-done barrier so global->LDS latency hides under PV; 2 waves x 32q;
// XCD swizzle; S^T form; fixed-m softmax; XOR-swizzled K/V staging.
__global__ __launch_bounds__(128, 3) void flash_kernel(const f16* __restrict__ Qh,
                                                       const f16* __restrict__ Kh,
                                                       const f16* __restrict__ Vt,
                                                       float* __restrict__ out) {
  int L = blockIdx.x;
  int xcd = L & 7, slot = L >> 3;
  int bh = ((slot >> 5) << 3) | xcd;  // 32 qt-blocks of bh share one XCD
  int qt = slot & 31;
  int b = bh >> 4, h = bh & 15;
  int tid = threadIdx.x;
  int lane = tid & 63, w = tid >> 6;  // w in {0,1}
  int l15 = lane & 15, quad = lane >> 4;
  int qrow0 = qt * 64 + w * 32;

  __shared__ alignas(16) f16 Kls[64 * 64];  // [t][d], XOR chunk swizzle by row&7
  __shared__ alignas(16) f16 Vls[64 * 64];  // [d][t], same swizzle

  const f16* kbase = Kh + (size_t)bh * SEQ * HD;
  const f16* vbase = Vt + (size_t)bh * HD * SEQ;

  // staging map: 128 threads, 4 rounds x (K,V); round rd covers rows rd*16 + (tid>>3)
  int srow = tid >> 3;  // 0..15
  int schunk = tid & 7;

  // Q fragments (B-operand for S^T = K Q^T), 2 q-tiles; fold in 1/sqrt(64)
  const f16* qptr = Qh + ((size_t)bh * SEQ + qrow0 + l15) * HD + quad * 8;
  half8 qf[2][2];
  qf[0][0] = *(const half8*)qptr;
  qf[0][1] = *(const half8*)(qptr + 32);
  qf[1][0] = *(const half8*)(qptr + 16 * HD);
  qf[1][1] = *(const half8*)(qptr + 16 * HD + 32);
#pragma unroll
  for (int q2 = 0; q2 < 2; q2++)
#pragma unroll
    for (int ks = 0; ks < 2; ks++)
#pragma unroll
      for (int j = 0; j < 8; j++) qf[q2][ks][j] *= (f16)0.125f;

  f32x4 zero = {0.f, 0.f, 0.f, 0.f};
  float l_acc[2] = {0.f, 0.f};
  f32x4 o[2][4];
#pragma unroll
  for (int q2 = 0; q2 < 2; q2++)
#pragma unroll
    for (int nt = 0; nt < 4; nt++) o[q2][nt] = zero;

  // swizzled LDS read offsets (halves): row*64 + (chunk ^ (row&7))*8
  int swz0 = (quad ^ (l15 & 7)) * 8;        // log chunks 0..3
  int swz1 = ((quad + 4) ^ (l15 & 7)) * 8;  // log chunks 4..7

  // cooperative staging: K tile (64t x 64d) + V tile (64d x 64t)
  auto stage = [&](int kv0) {
#pragma unroll
    for (int rd = 0; rd < 4; rd++) {
      int row = rd * 16 + srow;
      int pc = schunk ^ (row & 7);
      gload_lds16(kbase + ((size_t)(kv0 + row) << 6) + pc * 8,
                  &Kls[rd * 1024 + w * 512]);
      gload_lds16(vbase + ((size_t)row * SEQ) + kv0 + pc * 8,
                  &Vls[rd * 1024 + w * 512]);
    }
  };

  stage(0);

  for (int kv0 = 0; kv0 < SEQ; kv0 += 64) {
    __syncthreads();  // staged tile visible (barrier drains vmcnt)

    // ---- K fragments from LDS (shared across both q-tiles) ----
    half8 kf0[4], kf1[4];
#pragma unroll
    for (int tt = 0; tt < 4; tt++) {
      int row = tt * 16 + l15;
      kf0[tt] = *(const half8*)&Kls[row * 64 + swz0];
      kf1[tt] = *(const half8*)&Kls[row * 64 + swz1];
    }

    // ---- per q-tile: S^T, softmax, in-register P repack ----
    half8 pa[2][2];  // PV A-fragments, k-slice ks
#pragma unroll
    for (int q2 = 0; q2 < 2; q2++) {
      f32x4 sc[4];
#pragma unroll
      for (int tt = 0; tt < 4; tt++) {
        sc[tt] = __builtin_amdgcn_mfma_f32_16x16x32_f16(kf0[tt], qf[q2][0], zero, 0, 0, 0);
        sc[tt] = __builtin_amdgcn_mfma_f32_16x16x32_f16(kf1[tt], qf[q2][1], sc[tt], 0, 0, 0);
      }
      float ps = 0.f;
#pragma unroll
      for (int tt = 0; tt < 4; tt++)
#pragma unroll
        for (int r = 0; r < 4; r++) { sc[tt][r] = __expf(sc[tt][r]); ps += sc[tt][r]; }
      ps += __shfl_xor(ps, 16);
      ps += __shfl_xor(ps, 32);
      l_acc[q2] += ps;

      // pack P to f16 words: W[tt][0]=(p0,p1), W[tt][1]=(p2,p3)
      unsigned wp[4][2];
#pragma unroll
      for (int tt = 0; tt < 4; tt++) {
        wp[tt][0] = pk16(sc[tt][0], sc[tt][1]);
        wp[tt][1] = pk16(sc[tt][2], sc[tt][3]);
      }
      // route to A-fragment layout: pa[ks][j] = P[l15][ks*32+quad*8+j]
#pragma unroll
      for (int ks = 0; ks < 2; ks++) {
        u32x4 pw;
#pragma unroll
        for (int i = 0; i < 2; i++) {
          unsigned a, bb, x, y;
          swap32(wp[2 * ks][i], wp[2 * ks + 1][i], a, bb);
          swap16(a, bb, x, y);
          pw[i] = x;       // j = 4*i .. 4*i+1  (half 0)
          pw[2 + i] = y;   // j = 4+... (half 1)
        }
        pa[q2][ks] = __builtin_bit_cast(half8, pw);
      }
    }

    // ---- V fragments from LDS (shared across both q-tiles) ----
    half8 vf0[4], vf1[4];
#pragma unroll
    for (int nt = 0; nt < 4; nt++) {
      int row = nt * 16 + l15;
      vf0[nt] = *(const half8*)&Vls[row * 64 + swz0];
      vf1[nt] = *(const half8*)&Vls[row * 64 + swz1];
    }

    __syncthreads();  // all K/V LDS reads of this tile complete

    if (kv0 + 64 < SEQ) stage(kv0 + 64);  // issue next tile; hides under PV

    // ---- O += P V (pure register) ----
#pragma unroll
    for (int q2 = 0; q2 < 2; q2++)
#pragma unroll
      for (int ks = 0; ks < 2; ks++)
#pragma unroll
        for (int nt = 0; nt < 4; nt++)
          o[q2][nt] = __builtin_amdgcn_mfma_f32_16x16x32_f16(pa[q2][ks], ks ? vf1[nt] : vf0[nt], o[q2][nt], 0, 0, 0);
  }

#pragma unroll
  for (int q2 = 0; q2 < 2; q2++) {
    float linv[4];
#pragma unroll
    for (int r = 0; r < 4; r++) linv[r] = 1.0f / __shfl(l_acc[q2], quad * 4 + r);
#pragma unroll
    for (int nt = 0; nt < 4; nt++) {
#pragma unroll
      for (int r = 0; r < 4; r++) {
        int s = qrow0 + q2 * 16 + quad * 4 + r;
        out[((size_t)b * SEQ + s) * RES + h * HD + nt * 16 + l15] = o[q2][nt][r] * linv[r];
      }
    }
  }
}

extern "C" void kernel_launch(void* const* d_in, const int* in_sizes, int n_in,
                              void* d_out, int out_size, void* d_ws, size_t ws_size,
                              hipStream_t stream) {
  (void)in_sizes; (void)n_in; (void)out_size; (void)ws_size;
  const float* x  = (const float*)d_in[0];
  const float* Wq = (const float*)d_in[1];
  const float* Wk = (const float*)d_in[2];
  const float* Wv = (const float*)d_in[3];
  float* out = (float*)d_out;

  // workspace layout (fp16): xh 8MB | Wt 6MB | Qh 8MB | Kh 8MB | Vt 8MB = 38MB
  f16* xh = (f16*)d_ws;
  f16* Wt = xh + (size_t)M_ROWS * RES;
  f16* Qh = Wt + (size_t)3 * RES * RES;
  f16* Kh = Qh + (size_t)BATCH * NH * SEQ * HD;
  f16* Vt = Kh + (size_t)BATCH * NH * SEQ * HD;

  xconv_kernel<<<M_ROWS * RES / (256 * 8), 256, 0, stream>>>(x, xh);
  wtrans_kernel<<<dim3(32, 32, 3), dim3(32, 32), 0, stream>>>(Wq, Wk, Wv, Wt);
  proj_gemm_kernel<<<dim3(M_ROWS / 128, RES / 128, 3), 256, 0, stream>>>(xh, Wt, Qh, Kh, Vt);
  flash_kernel<<<1024, 128, 0, stream>>>(Qh, Kh, Vt, out);
}